// Round 7
// baseline (4583.638 us; speedup 1.0000x reference)
//
#include <hip/hip_runtime.h>
#include <math.h>

// ---------------------------------------------------------------------------
// DisableGateLSTM R11: R9 core + {flag-array barrier (no RMW chain), per-wave
// poll (B1 deleted), wide activations, b128 partial stores}.
// 256 blocks x 512 threads, 1 block/CU. 4 groups x 64 blocks; group g owns
// chains [16g,16g+16); block j owns hidden units [8j,8j+8) = 32 gate rows.
//
// R10 post-mortem: narrowing the reduce into the 128-thread gate phase put
// serial LDS reads on the critical path with SIMDs 2,3 idle -> +0.7us/step.
// RULE: keep inter-barrier phases 512-wide. R9 remains the verified base
// (4330us, VGPR 64, WRITE 70MB -> spill-free).
// R11 attacks the sync chain (R4->R9 showed compute/LDS cuts barely move
// dur; step is latency-bound):
//  1) cnt/gen RMW barrier -> per-block flags (16B stride, same 4KB region):
//     producers store flag[j]=t+1 (parallel, no 64-deep same-line RMW
//     serialization); consumers poll wave-parallel (lane l reads flag l,
//     __all(v>=t)). Saves the RMW chain + gen hop each step.
//  2) Every wave polls for itself -> no B1 barrier (5 -> 4 barriers/step);
//     a wave stages its h slice as soon as ITS poll passes.
//  3) Activations (3 sigmoid + 1 tanh) computed in the 512-wide reduce
//     phase (rr<24 branch is wave-uniform); narrow phase is just
//     cn=f*c+i*g, h=o*tanhf(cn), store -> flag flips sooner.
//  4) sPart stores as b128 [rank][ci*4+ri] (8 writers x stride 68 -> 32
//     distinct banks); reduce re-indexed, same order -> bit-identical.
// Per-output FMA order identical to R9 -> absmax 0.0 preserved.
//
//  * Weights in VGPRs (48 floats/thread, zero redundancy). 48 b128 LDS
//    reads/thread/step. 64-way k-split folded 8x in-wave via 3 DPP adds.
//  * PRS=68: do NOT change without re-deriving banks.
// Cross-block h exchange: relaxed agent-scope atomics (R1-proven).
// Gates use exact libm expf/tanhf.
// ---------------------------------------------------------------------------

#define BATCH   64
#define SEQ     512
#define EMBED   256
#define HIDDEN  512
#define GD      768
#define CLASSES 4

#define NBLK    256
#define NTHR    512
#define GROUPS  4
#define GB      64
#define CPG     16
#define UPB     8
#define ROWS    32

// LDS strides (floats)
#define SHS  520   // sH chain stride: 512 + 8 (odd bank-quad phase per chain)
#define SXS  264   // sX chain stride: 256 + 8
#define PRS  68    // partial-scratch rank stride: 64 data + 4 pad

typedef unsigned long long __attribute__((may_alias)) ull_a;

union F2U { float f[2]; unsigned long long u; };

// Sum over each aligned 8-lane group via DPP involutions (VALU pipe, no LDS).
__device__ __forceinline__ float dpp8_sum(float v) {
  int x;
  x = __builtin_amdgcn_update_dpp(0, __float_as_int(v), 0x141, 0xF, 0xF, false); // row_half_mirror
  v += __int_as_float(x);
  x = __builtin_amdgcn_update_dpp(0, __float_as_int(v), 0x4E,  0xF, 0xF, false); // quad_perm(2,3,0,1)
  v += __int_as_float(x);
  x = __builtin_amdgcn_update_dpp(0, __float_as_int(v), 0xB1,  0xF, 0xF, false); // quad_perm(1,0,3,2)
  v += __int_as_float(x);
  return v;
}

__global__ __launch_bounds__(NTHR) void lstm_persistent(
    const int*   __restrict__ ids,
    const float* __restrict__ emb,
    const float* __restrict__ Wf, const float* __restrict__ bf,
    const float* __restrict__ Wi, const float* __restrict__ bi,
    const float* __restrict__ Wo, const float* __restrict__ bo,
    const float* __restrict__ Wc, const float* __restrict__ bc,
    const float* __restrict__ fcw,
    const float* __restrict__ fcb,
    float* __restrict__ out,
    float* __restrict__ ws)
{
  __shared__ __align__(16) float sH[CPG * SHS];      // 33.3 KB
  __shared__ __align__(16) float sX[CPG * SXS];      // 16.9 KB
  __shared__ __align__(16) float sPart[64 * PRS];    // 17.4 KB
  __shared__ float sG[ROWS][CPG];                    // activations + head scratch
  __shared__ float sC[UPB][CPG];
  __shared__ float sM[UPB][CPG];
  __shared__ float sB[ROWS];

  const int tid = threadIdx.x;
  const int bid = blockIdx.x;
  const int g   = bid & 3;
  const int j   = bid >> 2;
  const int u0  = j * UPB;

  float*    hbufF   = ws;                                    // [2][64][512] f32
  ull_a*    hbufU   = (ull_a*)ws;                            // same, ull view
  float*    wmaxF   = ws + (size_t)2 * BATCH * HIDDEN;       // [64][512] f32
  ull_a*    wmaxU   = (ull_a*)wmaxF;
  // flags: [4 groups][64 blocks][4 dwords] = 4096 B (old barArea, memset 0)
  unsigned* flags   = (unsigned*)(ws + (size_t)3 * BATCH * HIDDEN);
  unsigned* myflag  = flags + g * 256 + j * 4;
  const unsigned* pollf = flags + g * 256 + (tid & 63) * 4;

  // ---- thread geometry ----
  const int sl = tid & 7;
  const int wv = tid >> 6;
  const int s  = sl + wv * 8;          // 0..63
  const int rg = (tid >> 3) & 7;       // 0..7

  // ---- weights -> VGPRs, once (48 floats/thread, no redundancy) ----
  float4 wh[4][2], wx4[4];
  {
    const float* Wg = (rg < 2) ? Wf : (rg < 4) ? Wi : (rg < 6) ? Wo : Wc;
    const int ub = u0 + (rg & 1) * 4;
    #pragma unroll
    for (int ri = 0; ri < 4; ++ri) {
      const float* row = Wg + (size_t)(ub + ri) * GD;
      wh[ri][0] = *(const float4*)(row + s * 8);
      wh[ri][1] = *(const float4*)(row + s * 8 + 4);
      wx4[ri]   = *(const float4*)(row + HIDDEN + s * 4);
    }
  }
  if (tid < ROWS) {
    const float* bv = (tid < 8) ? bf : (tid < 16) ? bi : (tid < 24) ? bo : bc;
    sB[tid] = bv[u0 + (tid & 7)];
  }
  if (tid < UPB * CPG) {
    ((float*)sC)[tid] = 0.0f;
    ((float*)sM)[tid] = -3.402823e38f;
  }

  // staging mapping (chain-major, 32 lanes/chain)
  const int stg_c = tid >> 5;
  const int stg_s = tid & 31;
  const int bStg  = g * CPG + stg_c;

  const float* pH = sH + s * 8;        // + ci*SHS via imm offsets
  const float* pX = sX + s * 4;

  // prefetch x_0 into registers
  float4 rx0, rx1;
  {
    int id0 = ids[(size_t)bStg * SEQ];
    const float4* xs = (const float4*)(emb + (size_t)id0 * EMBED);
    rx0 = xs[stg_s * 2];
    rx1 = xs[stg_s * 2 + 1];
  }

  for (int t = 0; t < SEQ; ++t) {
    const int pb = t & 1;

    // ---- stage x_t (register -> LDS); ordered vs GEMM by B2 ----
    {
      float* dx = sX + stg_c * SXS + stg_s * 8;
      *(float4*)dx = rx0;
      *(float4*)(dx + 4) = rx1;
    }

    // ---- per-wave poll: lane l watches block l's flag; no B1 needed ----
    {
      while (true) {
        unsigned v = __hip_atomic_load(pollf, __ATOMIC_RELAXED,
                                       __HIP_MEMORY_SCOPE_AGENT);
        if (__all((int)(v >= (unsigned)t))) break;
        __builtin_amdgcn_s_sleep(1);
      }
    }
    __atomic_signal_fence(__ATOMIC_ACQUIRE);

    // ---- stage h_t via coherent loads (this wave's slice only) ----
    {
      const ull_a* hs = hbufU + ((size_t)pb * BATCH + bStg) * (HIDDEN / 2);
      float* dh = sH + stg_c * SHS;
      #pragma unroll
      for (int kk = 0; kk < 8; ++kk) {
        unsigned long long v = __hip_atomic_load(hs + stg_s + kk * 32,
                                                 __ATOMIC_RELAXED,
                                                 __HIP_MEMORY_SCOPE_AGENT);
        *(ull_a*)(dh + 2 * stg_s + 64 * kk) = v;
      }
    }
    __syncthreads();                                   // B2: sX + sH ready

    // ---- fused x+h GEMM + DPP k-reduce + b128 partial store (R9 order) ----
    #pragma unroll
    for (int ci = 0; ci < 16; ++ci) {
      float4 xv = *(const float4*)(pX + ci * SXS);
      float4 h0 = *(const float4*)(pH + ci * SHS);
      float4 h1 = *(const float4*)(pH + ci * SHS + 4);
      float a[4];
      #pragma unroll
      for (int ri = 0; ri < 4; ++ri) {
        float t0;
        t0 = wx4[ri].x * xv.x;
        t0 = fmaf(wx4[ri].y, xv.y, t0);
        t0 = fmaf(wx4[ri].z, xv.z, t0);
        t0 = fmaf(wx4[ri].w, xv.w, t0);
        t0 = fmaf(wh[ri][0].x, h0.x, t0);
        t0 = fmaf(wh[ri][0].y, h0.y, t0);
        t0 = fmaf(wh[ri][0].z, h0.z, t0);
        t0 = fmaf(wh[ri][0].w, h0.w, t0);
        t0 = fmaf(wh[ri][1].x, h1.x, t0);
        t0 = fmaf(wh[ri][1].y, h1.y, t0);
        t0 = fmaf(wh[ri][1].z, h1.z, t0);
        t0 = fmaf(wh[ri][1].w, h1.w, t0);
        a[ri] = dpp8_sum(t0);
      }
      if ((tid & 7) == 0)
        *(float4*)(sPart + (tid >> 3) * PRS + ci * 4) =
            make_float4(a[0], a[1], a[2], a[3]);   // 8 writers, 32 banks
    }

    // ---- prefetch x_{t+1} ----
    {
      const int tn = (t + 1 < SEQ) ? t + 1 : SEQ - 1;
      int idn = ids[(size_t)bStg * SEQ + tn];
      const float4* xs = (const float4*)(emb + (size_t)idn * EMBED);
      rx0 = xs[stg_s * 2];
      rx1 = xs[stg_s * 2 + 1];
    }
    __syncthreads();                                   // B3: sPart ready

    // ---- 512-wide: cross-wave reduce (8 partials, w ascending, bias
    //      first = R9 order) + ACTIVATION (wave-uniform branch) ----
    {
      const int rr  = tid >> 4;            // row 0..31
      const int ci2 = tid & 15;            // chain
      const int rg2 = rr >> 2, ril = rr & 3;
      float ssum = sB[rr];
      #pragma unroll
      for (int w = 0; w < 8; ++w)
        ssum += sPart[(w * 8 + rg2) * PRS + ci2 * 4 + ril];
      // waves 0-5: sigmoid rows (f,i,o); waves 6-7: tanh rows (g)
      sG[rr][ci2] = (rr < 24) ? 1.0f / (1.0f + expf(-ssum)) : tanhf(ssum);
    }
    __syncthreads();                                   // B4: sG ready

    // ---- narrow phase (minimal): state update + coherent h store ----
    if (tid < 128) {
      const int u = tid & 7, ch = tid >> 3;
      float f  = sG[u][ch];
      float i_ = sG[8 + u][ch];
      float o  = sG[16 + u][ch];
      float gg = sG[24 + u][ch];
      float cn = f * sC[u][ch] + i_ * gg;
      float h  = o * tanhf(cn);
      sC[u][ch] = cn;
      sM[u][ch] = fmaxf(sM[u][ch], h);
      __hip_atomic_store(
          hbufF + ((size_t)(pb ^ 1) * BATCH + g * CPG + ch) * HIDDEN + u0 + u,
          h, __ATOMIC_RELAXED, __HIP_MEMORY_SCOPE_AGENT);
    }
    __syncthreads();   // B5: drains vmcnt -> h stores coherence-visible

    // ---- arrival: parallel per-block flag (no RMW chain) ----
    if (tid == 0)
      __hip_atomic_store(myflag, (unsigned)(t + 1), __ATOMIC_RELAXED,
                         __HIP_MEMORY_SCOPE_AGENT);
  }

  // ---- publish running max (coherent), final flag ----
  if (tid < 128) {
    const int u = tid & 7, ch = tid >> 3;
    __hip_atomic_store(wmaxF + (size_t)(g * CPG + ch) * HIDDEN + u0 + u,
                       sM[u][ch], __ATOMIC_RELAXED, __HIP_MEMORY_SCOPE_AGENT);
  }
  __syncthreads();   // drains vmcnt for wmax stores
  if (tid == 0)
    __hip_atomic_store(myflag, (unsigned)(SEQ + 1), __ATOMIC_RELAXED,
                       __HIP_MEMORY_SCOPE_AGENT);

  // ---- head GEMV on group-leader blocks ----
  if (j == 0) {
    {
      while (true) {
        unsigned v = __hip_atomic_load(pollf, __ATOMIC_RELAXED,
                                       __HIP_MEMORY_SCOPE_AGENT);
        if (__all((int)(v >= (unsigned)(SEQ + 1)))) break;
        __builtin_amdgcn_s_sleep(1);
      }
    }
    __atomic_signal_fence(__ATOMIC_ACQUIRE);

    const int ch = tid & 15, cls = (tid >> 4) & 3, us = tid >> 6;
    const ull_a* mrow = wmaxU + (size_t)(g * CPG + ch) * (HIDDEN / 2) + us * 32;
    const float* wrow = fcw + (size_t)cls * HIDDEN + us * 64;
    float sacc = 0.0f;
    for (int q = 0; q < 32; ++q) {
      F2U v;
      v.u = __hip_atomic_load(mrow + q, __ATOMIC_RELAXED,
                              __HIP_MEMORY_SCOPE_AGENT);
      sacc = fmaf(v.f[0], wrow[2 * q], sacc);
      sacc = fmaf(v.f[1], wrow[2 * q + 1], sacc);
    }
    float* red2 = &sG[0][0];
    red2[tid] = sacc;
    __syncthreads();
    if (tid < 64) {
      float tot = fcb[(tid >> 4) & 3];
      #pragma unroll
      for (int q = 0; q < 8; ++q) tot += red2[q * 64 + tid];
      out[(g * CPG + (tid & 15)) * CLASSES + ((tid >> 4) & 3)] = tot;
    }
  }
}

extern "C" void kernel_launch(void* const* d_in, const int* in_sizes, int n_in,
                              void* d_out, int out_size, void* d_ws, size_t ws_size,
                              hipStream_t stream) {
  const int*   ids = (const int*)  d_in[0];
  const float* emb = (const float*)d_in[1];
  const float* Wf  = (const float*)d_in[2];
  const float* bf  = (const float*)d_in[3];
  const float* Wi  = (const float*)d_in[4];
  const float* bi  = (const float*)d_in[5];
  const float* Wo  = (const float*)d_in[6];
  const float* bo  = (const float*)d_in[7];
  const float* Wc  = (const float*)d_in[8];
  const float* bc  = (const float*)d_in[9];
  const float* fcw = (const float*)d_in[10];
  const float* fcb = (const float*)d_in[11];

  // zero h0 (hbuf buffer 0) and the flags region
  hipMemsetAsync(d_ws, 0, (size_t)BATCH * HIDDEN * sizeof(float), stream);
  hipMemsetAsync((char*)d_ws + (size_t)3 * BATCH * HIDDEN * sizeof(float),
                 0, 4096, stream);

  lstm_persistent<<<dim3(NBLK), dim3(NTHR), 0, stream>>>(
      ids, emb, Wf, bf, Wi, bi, Wo, bo, Wc, bc, fcw, fcb,
      (float*)d_out, (float*)d_ws);
}